// Round 5
// baseline (120.468 us; speedup 1.0000x reference)
//
#include <hip/hip_runtime.h>
#include <cmath>

// Problem constants (from reference)
#define NUM_B 8
#define NUM_C 4
#define NUM_M 64
#define APT   4        // anchors per thread: 1024 blocks = 4/CU, LDS/VALU balanced
#define BLK   256
constexpr float MAX_POS_D2  = 20.0f * 20.0f;          // dxy_min < 20  <=> d2 < 400
constexpr float BG_POS_D2   = 30.0f * 30.0f;          // dxy_min >= 30 <=> d2 >= 900
constexpr float MAX_ANG     = 15.0f;
constexpr float BG_ANG      = 22.5f;                  // 1.5 * 15
constexpr float ALPHA_C     = 0.95f;
constexpr float EPS_C       = 1e-4f;

// ws layout (all zeroed by the memsetAsync in kernel_launch):
//   ws[0..31]  : 8 batches x {cls_sum, xy_sum, ang_sum, num_pos} as double
//   ws+32      : completion counter (int, in the 8 bytes after the doubles)
// NOTE (R3 lesson): no min-waves-per-EU bound — capping VGPRs at 64 makes the
// compiler sink the prefetched loads and kills the latency hiding.
__global__ __launch_bounds__(BLK) void focal_main(
    const float* __restrict__ cls,   // (B, A, 4)
    const float* __restrict__ reg,   // (B, A, 3)
    const float* __restrict__ anc,   // (A, 3)
    const float* __restrict__ ann,   // (B, M, 4)
    double* __restrict__ ws,
    float* __restrict__ out,
    int A, int total_blocks)
{
    const int b    = blockIdx.y;
    const int tid  = threadIdx.x;
    const int base = blockIdx.x * (BLK * APT);

    // ---- annotation load FIRST: it's on the critical path to __syncthreads.
    float4 an_raw;
    if (tid < NUM_M)
        an_raw = ((const float4*)(ann + (size_t)b * NUM_M * 4))[tid];

    // ---- prefetch all per-anchor data; latency drains under the min loop.
    float ax[APT], ay[APT], aal[APT];
    float4 cv[APT];
    float rx[APT], ry[APT], ra[APT];
    #pragma unroll
    for (int j = 0; j < APT; ++j) {
        const int a  = base + tid + j * BLK;
        const int ac = min(a, A - 1);                         // clamp for safety
        const float* ap = anc + 3 * (size_t)ac;
        ax[j] = ap[0]; ay[j] = ap[1]; aal[j] = ap[2];         // dwordx3
        cv[j] = *(const float4*)(cls + ((size_t)b * A + ac) * NUM_C);
        const float* rp = reg + ((size_t)b * A + ac) * 3;
        rx[j] = rp[0]; ry[j] = rp[1]; ra[j] = rp[2];          // dwordx3
    }

    // Stage annotations to LDS.
    // Min-loop form: argmin d2  <=>  argmax u = ax*anx + ay*any - rh,
    // rh = (anx^2+any^2)/2  (d2 = q - 2u, q = ax^2+ay^2 per-anchor const).
    // Invalid annotations: rh = 1e36 -> u ~ -1e36, finite, can never win.
    __shared__ float4 s_mins[NUM_M];   // (x, y, rh-masked, pad)
    __shared__ float4 s_ann[NUM_M];    // raw (x, y, alpha, label) for gather
    if (tid < NUM_M) {
        const float4 an = an_raw;
        const bool valid = (an.w != -1.0f);
        const float rh = valid ? 0.5f * fmaf(an.x, an.x, an.y * an.y) : 1e36f;
        s_mins[tid] = make_float4(an.x, an.y, rh, 0.0f);
        s_ann[tid]  = an;
    }
    __syncthreads();

    float ub[APT];     // running max of u
    int   ubi[APT];    // its index
    #pragma unroll
    for (int j = 0; j < APT; ++j) { ub[j] = -INFINITY; ubi[j] = 0; }

    // Branch-free argmax: 1 ds_read_b128 + APT x 5 VALU per annotation.
    #pragma unroll 16
    for (int m = 0; m < NUM_M; ++m) {
        const float4 an = s_mins[m];
        #pragma unroll
        for (int j = 0; j < APT; ++j) {
            const float t = fmaf(ay[j], an.y, -an.z);
            const float u = fmaf(ax[j], an.x, t);
            const bool gt = u > ub[j];               // strict: first max wins
            ub[j]  = gt ? u : ub[j];
            ubi[j] = gt ? m : ubi[j];
        }
    }

    float cls_s = 0.0f, xy_s = 0.0f, ang_s = 0.0f, pos_s = 0.0f;

    #pragma unroll
    for (int j = 0; j < APT; ++j) {
        const int a = base + tid + j * BLK;
        if (a >= A) continue;

        const float q  = fmaf(ax[j], ax[j], ay[j] * ay[j]);
        const float d2 = fmaf(-2.0f, ub[j], q);      // min squared xy distance
        const float4 ba = s_ann[ubi[j]];             // winner is always valid here
        const float  dal = fabsf(aal[j] - ba.z);

        const bool positive   = (d2 < MAX_POS_D2) && (dal < MAX_ANG);
        const bool background = (d2 >= BG_POS_D2) || (dal >= BG_ANG);

        int label = (int)ba.w;                       // trunc, matches astype(int32)
        label = min(max(label, 0), NUM_C - 1);

        // ----- classification (focal) loss -----
        const float cc[4] = {cv[j].x, cv[j].y, cv[j].z, cv[j].w};
        float acc = 0.0f;
        #pragma unroll
        for (int c = 0; c < NUM_C; ++c) {
            const float p = fminf(fmaxf(cc[c], EPS_C), 1.0f - EPS_C);
            const bool is1  = positive && (c == label);  // t == 1
            const float r   = is1 ? (1.0f - p) : p;
            const float af  = is1 ? ALPHA_C : (1.0f - ALPHA_C);
            const float omr = is1 ? p : (1.0f - p);      // 1 - r, >= EPS
            // loss = af * r^2 * (-log(1 - r)); native log (err << 0.179 thr)
            acc += af * r * r * (-__logf(omr));
        }
        cls_s += (positive || background) ? acc : 0.0f;  // t == -1 -> ignored

        // ----- regression loss (positives only) -----
        if (positive) {
            pos_s += 1.0f;
            const float dxr = fabsf((ba.x - ax[j]) - rx[j]);
            const float dyr = fabsf((ba.y - ay[j]) - ry[j]);
            const float lx = (dxr <= 1.0f / 9.0f) ? 4.5f * dxr * dxr : dxr - 1.0f / 18.0f;
            const float ly = (dyr <= 1.0f / 9.0f) ? 4.5f * dyr * dyr : dyr - 1.0f / 18.0f;
            xy_s += lx + ly;
            const float dar = fabsf((ba.z - aal[j]) - ra[j]);
            ang_s += fmaxf((dar - 10.0f) * 0.2f, 0.0f);
        }
    }

    // ----- block reduction: wave64 shuffle -> LDS -> one atomic per block -----
    #pragma unroll
    for (int off = 32; off > 0; off >>= 1) {
        cls_s += __shfl_down(cls_s, off, 64);
        xy_s  += __shfl_down(xy_s,  off, 64);
        ang_s += __shfl_down(ang_s, off, 64);
        pos_s += __shfl_down(pos_s, off, 64);
    }
    __shared__ float s_red[BLK / 64][4];
    const int wave = tid >> 6;
    const int lane = tid & 63;
    if (lane == 0) {
        s_red[wave][0] = cls_s;
        s_red[wave][1] = xy_s;
        s_red[wave][2] = ang_s;
        s_red[wave][3] = pos_s;
    }
    __syncthreads();

    if (tid == 0) {
        float c0 = 0.0f, c1 = 0.0f, c2 = 0.0f, c3 = 0.0f;
        #pragma unroll
        for (int w = 0; w < BLK / 64; ++w) {
            c0 += s_red[w][0];
            c1 += s_red[w][1];
            c2 += s_red[w][2];
            c3 += s_red[w][3];
        }
        atomicAdd(&ws[b * 4 + 0], (double)c0);
        atomicAdd(&ws[b * 4 + 1], (double)c1);
        atomicAdd(&ws[b * 4 + 2], (double)c2);
        atomicAdd(&ws[b * 4 + 3], (double)c3);

        // ----- fused finalize: last block to finish does the reduction -----
        __threadfence();                              // release our ws adds
        int* counter = (int*)(ws + NUM_B * 4);
        const int old = atomicAdd(counter, 1);
        if (old == total_blocks - 1) {                // we're last: all adds visible
            __threadfence();
            double sc = 0.0, sx = 0.0, sg = 0.0;
            #pragma unroll
            for (int bb = 0; bb < NUM_B; ++bb) {
                // agent-scope atomic loads: coherent across XCDs
                const double s0 = __hip_atomic_load(&ws[bb * 4 + 0], __ATOMIC_RELAXED, __HIP_MEMORY_SCOPE_AGENT);
                const double s1 = __hip_atomic_load(&ws[bb * 4 + 1], __ATOMIC_RELAXED, __HIP_MEMORY_SCOPE_AGENT);
                const double s2 = __hip_atomic_load(&ws[bb * 4 + 2], __ATOMIC_RELAXED, __HIP_MEMORY_SCOPE_AGENT);
                const double s3 = __hip_atomic_load(&ws[bb * 4 + 3], __ATOMIC_RELAXED, __HIP_MEMORY_SCOPE_AGENT);
                const double denom = fmax(s3, 1.0);
                sc += s0 / denom;
                sx += s1 / (2.0 * denom);
                sg += s2 / denom;
            }
            out[0] = (float)(sc / (double)NUM_B);
            out[1] = (float)(sx / (double)NUM_B);
            out[2] = (float)(sg / (double)NUM_B);
        }
    }
}

extern "C" void kernel_launch(void* const* d_in, const int* in_sizes, int n_in,
                              void* d_out, int out_size, void* d_ws, size_t ws_size,
                              hipStream_t stream)
{
    const float* cls = (const float*)d_in[0];   // (B, A, 4)
    const float* reg = (const float*)d_in[1];   // (B, A, 3)
    const float* anc = (const float*)d_in[2];   // (1, A, 3)
    const float* ann = (const float*)d_in[3];   // (B, M, 4)
    const int A = in_sizes[2] / 3;

    double* ws = (double*)d_ws;
    // zero 8x4 double sums + counter (8 bytes after them)
    hipMemsetAsync(d_ws, 0, (NUM_B * 4 + 1) * sizeof(double), stream);

    dim3 grid((A + BLK * APT - 1) / (BLK * APT), NUM_B);
    const int total_blocks = grid.x * grid.y;
    focal_main<<<grid, BLK, 0, stream>>>(cls, reg, anc, ann, ws, (float*)d_out,
                                         A, total_blocks);
}

// Round 6
// 99.594 us; speedup vs baseline: 1.2096x; 1.2096x over previous
//
#include <hip/hip_runtime.h>
#include <cmath>

// Problem constants (from reference)
#define NUM_B 8
#define NUM_C 4
#define NUM_M 64
#define APT   8        // anchors per thread -> 512 blocks (best measured point)
#define BLK   256
constexpr float MAX_POS_D2  = 20.0f * 20.0f;          // dxy_min < 20  <=> d2 < 400
constexpr float BG_POS_D2   = 30.0f * 30.0f;          // dxy_min >= 30 <=> d2 >= 900
constexpr float MAX_ANG     = 15.0f;
constexpr float BG_ANG      = 22.5f;                  // 1.5 * 15
constexpr float ALPHA_C     = 0.95f;
constexpr float EPS_C       = 1e-4f;

// ws layout (doubles):
//   ws[0]            : completion counter (int in first 4 bytes; own 128B line)
//   ws[16 + 4*s ...] : per-block partial slot s = b*gridx + blockIdx.x,
//                      {cls_sum, xy_sum, ang_sum, num_pos} — plain stores, no
//                      contention (R5 lesson: per-block f64 atomics to shared
//                      lines serialized ~22us per 1024 blocks).
__global__ __launch_bounds__(BLK) void focal_main(
    const float* __restrict__ cls,   // (B, A, 4)
    const float* __restrict__ reg,   // (B, A, 3)
    const float* __restrict__ anc,   // (A, 3)
    const float* __restrict__ ann,   // (B, M, 4)
    double* __restrict__ ws,
    float* __restrict__ out,
    int A, int gridx)
{
    const int b    = blockIdx.y;
    const int tid  = threadIdx.x;
    const int base = blockIdx.x * (BLK * APT);
    const int total_blocks = gridx * NUM_B;

    // ---- annotation load first (critical path to the barrier) ----
    float4 an_raw;
    if (tid < NUM_M)
        an_raw = ((const float4*)(ann + (size_t)b * NUM_M * 4))[tid];

    // ---- prefetch ALL per-anchor data; sched_barrier below pins these loads
    // above the min loop so their latency drains under it (R3/R5 lesson: the
    // scheduler otherwise sinks them to their uses and exposes full latency).
    float ax[APT], ay[APT], aal[APT];
    float4 cv[APT];
    float rx[APT], ry[APT], ra[APT];
    #pragma unroll
    for (int j = 0; j < APT; ++j) {
        const int a  = base + tid + j * BLK;
        const int ac = min(a, A - 1);                         // clamp for safety
        const float* ap = anc + 3 * (size_t)ac;
        ax[j] = ap[0]; ay[j] = ap[1]; aal[j] = ap[2];         // dwordx3
        cv[j] = *(const float4*)(cls + ((size_t)b * A + ac) * NUM_C);
        const float* rp = reg + ((size_t)b * A + ac) * 3;
        rx[j] = rp[0]; ry[j] = rp[1]; ra[j] = rp[2];          // dwordx3
    }
    __builtin_amdgcn_sched_barrier(0);   // nothing moves across: loads stay up here

    // Stage annotations to LDS.
    // Min-loop form: argmin d2  <=>  argmax u = ax*anx + ay*any - rh,
    // rh = (anx^2+any^2)/2  (d2 = q - 2u, q = ax^2+ay^2 per-anchor const).
    // Invalid annotations: rh = 1e36 -> u ~ -1e36, finite, can never win.
    __shared__ float4 s_mins[NUM_M];   // (x, y, rh-masked, pad)
    __shared__ float4 s_ann[NUM_M];    // raw (x, y, alpha, label) for gather
    if (tid < NUM_M) {
        const float4 an = an_raw;
        const bool valid = (an.w != -1.0f);
        const float rh = valid ? 0.5f * fmaf(an.x, an.x, an.y * an.y) : 1e36f;
        s_mins[tid] = make_float4(an.x, an.y, rh, 0.0f);
        s_ann[tid]  = an;
    }
    __syncthreads();

    float ub[APT];     // running max of u
    int   ubi[APT];    // its index
    #pragma unroll
    for (int j = 0; j < APT; ++j) { ub[j] = -INFINITY; ubi[j] = 0; }

    // Branch-free argmax: 1 ds_read_b128 + APT x 5 VALU per annotation.
    #pragma unroll 16
    for (int m = 0; m < NUM_M; ++m) {
        const float4 an = s_mins[m];
        #pragma unroll
        for (int j = 0; j < APT; ++j) {
            const float t = fmaf(ay[j], an.y, -an.z);
            const float u = fmaf(ax[j], an.x, t);
            const bool gt = u > ub[j];               // strict: first max wins
            ub[j]  = gt ? u : ub[j];
            ubi[j] = gt ? m : ubi[j];
        }
    }

    float cls_s = 0.0f, xy_s = 0.0f, ang_s = 0.0f, pos_s = 0.0f;

    #pragma unroll
    for (int j = 0; j < APT; ++j) {
        const int a = base + tid + j * BLK;
        if (a >= A) continue;

        const float q  = fmaf(ax[j], ax[j], ay[j] * ay[j]);
        const float d2 = fmaf(-2.0f, ub[j], q);      // min squared xy distance
        const float4 ba = s_ann[ubi[j]];             // winner is always valid here
        const float  dal = fabsf(aal[j] - ba.z);

        const bool positive   = (d2 < MAX_POS_D2) && (dal < MAX_ANG);
        const bool background = (d2 >= BG_POS_D2) || (dal >= BG_ANG);

        int label = (int)ba.w;                       // trunc, matches astype(int32)
        label = min(max(label, 0), NUM_C - 1);

        // ----- classification (focal) loss -----
        const float cc[4] = {cv[j].x, cv[j].y, cv[j].z, cv[j].w};
        float acc = 0.0f;
        #pragma unroll
        for (int c = 0; c < NUM_C; ++c) {
            const float p = fminf(fmaxf(cc[c], EPS_C), 1.0f - EPS_C);
            const bool is1  = positive && (c == label);  // t == 1
            const float r   = is1 ? (1.0f - p) : p;
            const float af  = is1 ? ALPHA_C : (1.0f - ALPHA_C);
            const float omr = is1 ? p : (1.0f - p);      // 1 - r, >= EPS
            // loss = af * r^2 * (-log(1 - r)); native log (err << 0.179 thr)
            acc += af * r * r * (-__logf(omr));
        }
        cls_s += (positive || background) ? acc : 0.0f;  // t == -1 -> ignored

        // ----- regression loss (positives only) -----
        if (positive) {
            pos_s += 1.0f;
            const float dxr = fabsf((ba.x - ax[j]) - rx[j]);
            const float dyr = fabsf((ba.y - ay[j]) - ry[j]);
            const float lx = (dxr <= 1.0f / 9.0f) ? 4.5f * dxr * dxr : dxr - 1.0f / 18.0f;
            const float ly = (dyr <= 1.0f / 9.0f) ? 4.5f * dyr * dyr : dyr - 1.0f / 18.0f;
            xy_s += lx + ly;
            const float dar = fabsf((ba.z - aal[j]) - ra[j]);
            ang_s += fmaxf((dar - 10.0f) * 0.2f, 0.0f);
        }
    }

    // ----- block reduction: wave64 shuffle -> LDS -> per-block slot store -----
    #pragma unroll
    for (int off = 32; off > 0; off >>= 1) {
        cls_s += __shfl_down(cls_s, off, 64);
        xy_s  += __shfl_down(xy_s,  off, 64);
        ang_s += __shfl_down(ang_s, off, 64);
        pos_s += __shfl_down(pos_s, off, 64);
    }
    __shared__ float s_red[BLK / 64][4];
    __shared__ int   s_last;
    const int wave = tid >> 6;
    const int lane64 = tid & 63;
    if (lane64 == 0) {
        s_red[wave][0] = cls_s;
        s_red[wave][1] = xy_s;
        s_red[wave][2] = ang_s;
        s_red[wave][3] = pos_s;
    }
    __syncthreads();

    if (tid == 0) {
        float c0 = 0.0f, c1 = 0.0f, c2 = 0.0f, c3 = 0.0f;
        #pragma unroll
        for (int w = 0; w < BLK / 64; ++w) {
            c0 += s_red[w][0];
            c1 += s_red[w][1];
            c2 += s_red[w][2];
            c3 += s_red[w][3];
        }
        // unique slot per block: contention-free plain (agent-scope) stores
        double* slot = ws + 16 + 4 * (size_t)(b * gridx + blockIdx.x);
        __hip_atomic_store(&slot[0], (double)c0, __ATOMIC_RELAXED, __HIP_MEMORY_SCOPE_AGENT);
        __hip_atomic_store(&slot[1], (double)c1, __ATOMIC_RELAXED, __HIP_MEMORY_SCOPE_AGENT);
        __hip_atomic_store(&slot[2], (double)c2, __ATOMIC_RELAXED, __HIP_MEMORY_SCOPE_AGENT);
        __hip_atomic_store(&slot[3], (double)c3, __ATOMIC_RELAXED, __HIP_MEMORY_SCOPE_AGENT);
        // single RMW per block; ACQ_REL: releases our stores, last one acquires all
        int* counter = (int*)ws;
        const int old = __hip_atomic_fetch_add(counter, 1, __ATOMIC_ACQ_REL,
                                               __HIP_MEMORY_SCOPE_AGENT);
        s_last = (old == total_blocks - 1);
    }
    __syncthreads();

    // ----- fused finalize: last block reduces all slots (s_last is uniform) ----
    if (s_last) {
        __threadfence();                          // cache-coherent reads below
        const int bb   = tid >> 5;                // 8 batches x 32 lanes
        const int lane = tid & 31;
        double p0 = 0.0, p1 = 0.0, p2 = 0.0, p3 = 0.0;
        for (int s = lane; s < gridx; s += 32) {
            const double* sl = ws + 16 + 4 * (size_t)(bb * gridx + s);
            p0 += __hip_atomic_load(&sl[0], __ATOMIC_RELAXED, __HIP_MEMORY_SCOPE_AGENT);
            p1 += __hip_atomic_load(&sl[1], __ATOMIC_RELAXED, __HIP_MEMORY_SCOPE_AGENT);
            p2 += __hip_atomic_load(&sl[2], __ATOMIC_RELAXED, __HIP_MEMORY_SCOPE_AGENT);
            p3 += __hip_atomic_load(&sl[3], __ATOMIC_RELAXED, __HIP_MEMORY_SCOPE_AGENT);
        }
        #pragma unroll
        for (int off = 16; off > 0; off >>= 1) {
            p0 += __shfl_down(p0, off, 32);
            p1 += __shfl_down(p1, off, 32);
            p2 += __shfl_down(p2, off, 32);
            p3 += __shfl_down(p3, off, 32);
        }
        __shared__ double s_fin[NUM_B][4];
        if (lane == 0) {
            s_fin[bb][0] = p0; s_fin[bb][1] = p1;
            s_fin[bb][2] = p2; s_fin[bb][3] = p3;
        }
        __syncthreads();
        if (tid == 0) {
            double sc = 0.0, sx = 0.0, sg = 0.0;
            #pragma unroll
            for (int k = 0; k < NUM_B; ++k) {
                const double denom = fmax(s_fin[k][3], 1.0);
                sc += s_fin[k][0] / denom;
                sx += s_fin[k][1] / (2.0 * denom);
                sg += s_fin[k][2] / denom;
            }
            out[0] = (float)(sc / (double)NUM_B);
            out[1] = (float)(sx / (double)NUM_B);
            out[2] = (float)(sg / (double)NUM_B);
        }
    }
}

extern "C" void kernel_launch(void* const* d_in, const int* in_sizes, int n_in,
                              void* d_out, int out_size, void* d_ws, size_t ws_size,
                              hipStream_t stream)
{
    const float* cls = (const float*)d_in[0];   // (B, A, 4)
    const float* reg = (const float*)d_in[1];   // (B, A, 3)
    const float* anc = (const float*)d_in[2];   // (1, A, 3)
    const float* ann = (const float*)d_in[3];   // (B, M, 4)
    const int A = in_sizes[2] / 3;

    double* ws = (double*)d_ws;
    // only the counter line needs zeroing; slots are fully overwritten
    hipMemsetAsync(d_ws, 0, 128, stream);

    dim3 grid((A + BLK * APT - 1) / (BLK * APT), NUM_B);
    focal_main<<<grid, BLK, 0, stream>>>(cls, reg, anc, ann, ws, (float*)d_out,
                                         A, (int)grid.x);
}

// Round 7
// 98.593 us; speedup vs baseline: 1.2219x; 1.0102x over previous
//
#include <hip/hip_runtime.h>
#include <cmath>

// Problem constants (from reference)
#define NUM_B 8
#define NUM_C 4
#define NUM_M 64
#define APT   8        // anchors per thread
#define BLK   512      // 512 thr x APT 8 -> grid 32x8 = 256 blocks = 1 per CU
constexpr float MAX_POS_D2  = 20.0f * 20.0f;          // dxy_min < 20  <=> d2 < 400
constexpr float BG_POS_D2   = 30.0f * 30.0f;          // dxy_min >= 30 <=> d2 >= 900
constexpr float MAX_ANG     = 15.0f;
constexpr float BG_ANG      = 22.5f;                  // 1.5 * 15
constexpr float ALPHA_C     = 0.95f;
constexpr float EPS_C       = 1e-4f;

// R1..R6 lesson: focal_main time tracks WORKGROUP COUNT (~25ns/block ramp):
// 4096 blk=124us, 2048=67, 1024=45-48, 512=~28. So: fewest blocks that still
// covers all 256 CUs = 256 blocks (this config).
//
// ws layout (doubles):
//   ws[0]            : completion counter (int in first 4 bytes; own 128B line)
//   ws[16 + 4*s ...] : per-block partial slot s = b*gridx + blockIdx.x
__global__ __launch_bounds__(BLK) void focal_main(
    const float* __restrict__ cls,   // (B, A, 4)
    const float* __restrict__ reg,   // (B, A, 3)
    const float* __restrict__ anc,   // (A, 3)
    const float* __restrict__ ann,   // (B, M, 4)
    double* __restrict__ ws,
    float* __restrict__ out,
    int A, int gridx)
{
    const int b    = blockIdx.y;
    const int tid  = threadIdx.x;
    const int base = blockIdx.x * (BLK * APT);
    const int total_blocks = gridx * NUM_B;

    // ---- annotation load first (critical path to the barrier) ----
    float4 an_raw;
    if (tid < NUM_M)
        an_raw = ((const float4*)(ann + (size_t)b * NUM_M * 4))[tid];

    // ---- anchor loads SECOND: the min loop's s_waitcnt only needs these,
    // so grouping them before cls/reg leaves cls/reg in flight during the
    // min loop (R6 interleaved per-j and forced a near-full vmcnt drain).
    float ax[APT], ay[APT], aal[APT];
    #pragma unroll
    for (int j = 0; j < APT; ++j) {
        const int a  = base + tid + j * BLK;
        const int ac = min(a, A - 1);                         // clamp for safety
        const float* ap = anc + 3 * (size_t)ac;
        ax[j] = ap[0]; ay[j] = ap[1]; aal[j] = ap[2];
    }
    // ---- cls/reg LAST: latency drains under the ~5K-cycle min loop.
    float4 cv[APT];
    float rx[APT], ry[APT], ra[APT];
    #pragma unroll
    for (int j = 0; j < APT; ++j) {
        const int a  = base + tid + j * BLK;
        const int ac = min(a, A - 1);
        cv[j] = *(const float4*)(cls + ((size_t)b * A + ac) * NUM_C);
        const float* rp = reg + ((size_t)b * A + ac) * 3;
        rx[j] = rp[0]; ry[j] = rp[1]; ra[j] = rp[2];
    }
    __builtin_amdgcn_sched_barrier(0);   // loads stay above; nothing sinks them

    // Stage annotations to LDS.
    // Min-loop form: argmin d2  <=>  argmax u = ax*anx + ay*any - rh,
    // rh = (anx^2+any^2)/2  (d2 = q - 2u, q = ax^2+ay^2 per-anchor const).
    // Invalid annotations: rh = 1e36 -> u ~ -1e36, finite, can never win.
    __shared__ float4 s_mins[NUM_M];   // (x, y, rh-masked, pad)
    __shared__ float4 s_ann[NUM_M];    // raw (x, y, alpha, label) for gather
    if (tid < NUM_M) {
        const float4 an = an_raw;
        const bool valid = (an.w != -1.0f);
        const float rh = valid ? 0.5f * fmaf(an.x, an.x, an.y * an.y) : 1e36f;
        s_mins[tid] = make_float4(an.x, an.y, rh, 0.0f);
        s_ann[tid]  = an;
    }
    __syncthreads();

    float ub[APT];     // running max of u
    int   ubi[APT];    // its index
    #pragma unroll
    for (int j = 0; j < APT; ++j) { ub[j] = -INFINITY; ubi[j] = 0; }

    // Branch-free argmax: 1 ds_read_b128 + APT x 5 VALU per annotation.
    #pragma unroll 16
    for (int m = 0; m < NUM_M; ++m) {
        const float4 an = s_mins[m];
        #pragma unroll
        for (int j = 0; j < APT; ++j) {
            const float t = fmaf(ay[j], an.y, -an.z);
            const float u = fmaf(ax[j], an.x, t);
            const bool gt = u > ub[j];               // strict: first max wins
            ub[j]  = gt ? u : ub[j];
            ubi[j] = gt ? m : ubi[j];
        }
    }

    float cls_s = 0.0f, xy_s = 0.0f, ang_s = 0.0f, pos_s = 0.0f;

    #pragma unroll
    for (int j = 0; j < APT; ++j) {
        const int a = base + tid + j * BLK;
        if (a >= A) continue;

        const float q  = fmaf(ax[j], ax[j], ay[j] * ay[j]);
        const float d2 = fmaf(-2.0f, ub[j], q);      // min squared xy distance
        const float4 ba = s_ann[ubi[j]];             // winner is always valid here
        const float  dal = fabsf(aal[j] - ba.z);

        const bool positive   = (d2 < MAX_POS_D2) && (dal < MAX_ANG);
        const bool background = (d2 >= BG_POS_D2) || (dal >= BG_ANG);

        int label = (int)ba.w;                       // trunc, matches astype(int32)
        label = min(max(label, 0), NUM_C - 1);

        // ----- classification (focal) loss -----
        const float cc[4] = {cv[j].x, cv[j].y, cv[j].z, cv[j].w};
        float acc = 0.0f;
        #pragma unroll
        for (int c = 0; c < NUM_C; ++c) {
            const float p = fminf(fmaxf(cc[c], EPS_C), 1.0f - EPS_C);
            const bool is1  = positive && (c == label);  // t == 1
            const float r   = is1 ? (1.0f - p) : p;
            const float af  = is1 ? ALPHA_C : (1.0f - ALPHA_C);
            const float omr = is1 ? p : (1.0f - p);      // 1 - r, >= EPS
            // loss = af * r^2 * (-log(1 - r)); native log (err << 0.179 thr)
            acc += af * r * r * (-__logf(omr));
        }
        cls_s += (positive || background) ? acc : 0.0f;  // t == -1 -> ignored

        // ----- regression loss (positives only) -----
        if (positive) {
            pos_s += 1.0f;
            const float dxr = fabsf((ba.x - ax[j]) - rx[j]);
            const float dyr = fabsf((ba.y - ay[j]) - ry[j]);
            const float lx = (dxr <= 1.0f / 9.0f) ? 4.5f * dxr * dxr : dxr - 1.0f / 18.0f;
            const float ly = (dyr <= 1.0f / 9.0f) ? 4.5f * dyr * dyr : dyr - 1.0f / 18.0f;
            xy_s += lx + ly;
            const float dar = fabsf((ba.z - aal[j]) - ra[j]);
            ang_s += fmaxf((dar - 10.0f) * 0.2f, 0.0f);
        }
    }

    // ----- block reduction: wave64 shuffle -> LDS -> per-block slot store -----
    #pragma unroll
    for (int off = 32; off > 0; off >>= 1) {
        cls_s += __shfl_down(cls_s, off, 64);
        xy_s  += __shfl_down(xy_s,  off, 64);
        ang_s += __shfl_down(ang_s, off, 64);
        pos_s += __shfl_down(pos_s, off, 64);
    }
    __shared__ float s_red[BLK / 64][4];
    __shared__ int   s_last;
    const int wave = tid >> 6;
    const int lane64 = tid & 63;
    if (lane64 == 0) {
        s_red[wave][0] = cls_s;
        s_red[wave][1] = xy_s;
        s_red[wave][2] = ang_s;
        s_red[wave][3] = pos_s;
    }
    __syncthreads();

    if (tid == 0) {
        float c0 = 0.0f, c1 = 0.0f, c2 = 0.0f, c3 = 0.0f;
        #pragma unroll
        for (int w = 0; w < BLK / 64; ++w) {
            c0 += s_red[w][0];
            c1 += s_red[w][1];
            c2 += s_red[w][2];
            c3 += s_red[w][3];
        }
        // unique slot per block: contention-free agent-scope stores
        double* slot = ws + 16 + 4 * (size_t)(b * gridx + blockIdx.x);
        __hip_atomic_store(&slot[0], (double)c0, __ATOMIC_RELAXED, __HIP_MEMORY_SCOPE_AGENT);
        __hip_atomic_store(&slot[1], (double)c1, __ATOMIC_RELAXED, __HIP_MEMORY_SCOPE_AGENT);
        __hip_atomic_store(&slot[2], (double)c2, __ATOMIC_RELAXED, __HIP_MEMORY_SCOPE_AGENT);
        __hip_atomic_store(&slot[3], (double)c3, __ATOMIC_RELAXED, __HIP_MEMORY_SCOPE_AGENT);
        // single RMW per block; ACQ_REL: releases our stores, last one acquires all
        int* counter = (int*)ws;
        const int old = __hip_atomic_fetch_add(counter, 1, __ATOMIC_ACQ_REL,
                                               __HIP_MEMORY_SCOPE_AGENT);
        s_last = (old == total_blocks - 1);
    }
    __syncthreads();

    // ----- fused finalize: last block reduces all slots (s_last is uniform) ----
    if (s_last) {
        __threadfence();
        const int bb   = tid >> 6;                // 8 batches x 64 lanes (BLK=512)
        const int lane = tid & 63;
        double p0 = 0.0, p1 = 0.0, p2 = 0.0, p3 = 0.0;
        for (int s = lane; s < gridx; s += 64) {
            const double* sl = ws + 16 + 4 * (size_t)(bb * gridx + s);
            p0 += __hip_atomic_load(&sl[0], __ATOMIC_RELAXED, __HIP_MEMORY_SCOPE_AGENT);
            p1 += __hip_atomic_load(&sl[1], __ATOMIC_RELAXED, __HIP_MEMORY_SCOPE_AGENT);
            p2 += __hip_atomic_load(&sl[2], __ATOMIC_RELAXED, __HIP_MEMORY_SCOPE_AGENT);
            p3 += __hip_atomic_load(&sl[3], __ATOMIC_RELAXED, __HIP_MEMORY_SCOPE_AGENT);
        }
        #pragma unroll
        for (int off = 32; off > 0; off >>= 1) {
            p0 += __shfl_down(p0, off, 64);
            p1 += __shfl_down(p1, off, 64);
            p2 += __shfl_down(p2, off, 64);
            p3 += __shfl_down(p3, off, 64);
        }
        __shared__ double s_fin[NUM_B][4];
        if (lane == 0) {
            s_fin[bb][0] = p0; s_fin[bb][1] = p1;
            s_fin[bb][2] = p2; s_fin[bb][3] = p3;
        }
        __syncthreads();
        if (tid == 0) {
            double sc = 0.0, sx = 0.0, sg = 0.0;
            #pragma unroll
            for (int k = 0; k < NUM_B; ++k) {
                const double denom = fmax(s_fin[k][3], 1.0);
                sc += s_fin[k][0] / denom;
                sx += s_fin[k][1] / (2.0 * denom);
                sg += s_fin[k][2] / denom;
            }
            out[0] = (float)(sc / (double)NUM_B);
            out[1] = (float)(sx / (double)NUM_B);
            out[2] = (float)(sg / (double)NUM_B);
        }
    }
}

extern "C" void kernel_launch(void* const* d_in, const int* in_sizes, int n_in,
                              void* d_out, int out_size, void* d_ws, size_t ws_size,
                              hipStream_t stream)
{
    const float* cls = (const float*)d_in[0];   // (B, A, 4)
    const float* reg = (const float*)d_in[1];   // (B, A, 3)
    const float* anc = (const float*)d_in[2];   // (1, A, 3)
    const float* ann = (const float*)d_in[3];   // (B, M, 4)
    const int A = in_sizes[2] / 3;

    double* ws = (double*)d_ws;
    // only the counter line needs zeroing; slots are fully overwritten
    hipMemsetAsync(d_ws, 0, 128, stream);

    dim3 grid((A + BLK * APT - 1) / (BLK * APT), NUM_B);   // 32 x 8 = 256 blocks
    focal_main<<<grid, BLK, 0, stream>>>(cls, reg, anc, ann, ws, (float*)d_out,
                                         A, (int)grid.x);
}

// Round 8
// 92.303 us; speedup vs baseline: 1.3051x; 1.0682x over previous
//
#include <hip/hip_runtime.h>
#include <cmath>

// Problem constants (from reference)
#define NUM_B 8
#define NUM_C 4
#define NUM_M 64
#define APT   8        // anchors per thread
#define BLK   512      // grid 32x8 = 256 blocks = 1 per CU
#define GCELL 16       // 16x16 cells of 32px over the 512px image
constexpr float MAX_POS_D2  = 20.0f * 20.0f;          // dxy_min < 20  <=> d2 < 400
constexpr float BG_POS_D2   = 30.0f * 30.0f;          // dxy_min >= 30 <=> d2 >= 900
constexpr float MAX_ANG     = 15.0f;
constexpr float BG_ANG      = 22.5f;                  // 1.5 * 15
constexpr float ALPHA_C     = 0.95f;
constexpr float EPS_C       = 1e-4f;
// cell dilation: 30 + 16*sqrt(2) = 52.63px -> r^2 = 2769.7; 2775 = safety pad
constexpr float DILATE_R    = 52.64f;
constexpr float DILATE_R2   = 2775.0f;

// R1..R7 lessons: time tracks the 64-iteration min loop's per-iteration cost
// (~60cyc/iter incl. issue+latency), NOT VALU flops, occupancy, or block count.
// This version cuts trip count ~10x via an EXACT spatial bitmask grid:
//   - ann m set in cell c iff dist(ann, center(c)) <= 30+halfdiag
//   - anchor scans only its own cell's mask (avg ~1.6 candidates)
//   - list-min < 900  => equals global argmin (true argmin within 30px => in mask)
//   - list-min >= 900 => background; argmin identity provably irrelevant
//
// ws layout (doubles):
//   ws[0]            : completion counter (int in first 4 bytes)
//   ws[16 + 4*s ...] : per-block partial slot s = b*gridx + blockIdx.x
__global__ __launch_bounds__(BLK) void focal_main(
    const float* __restrict__ cls,   // (B, A, 4)
    const float* __restrict__ reg,   // (B, A, 3)
    const float* __restrict__ anc,   // (A, 3)
    const float* __restrict__ ann,   // (B, M, 4)
    double* __restrict__ ws,
    float* __restrict__ out,
    int A, int gridx)
{
    const int b    = blockIdx.y;
    const int tid  = threadIdx.x;
    const int base = blockIdx.x * (BLK * APT);
    const int total_blocks = gridx * NUM_B;

    __shared__ float4 s_ann[NUM_M];                    // raw (x, y, alpha, label)
    __shared__ __align__(8) unsigned int s_mask[GCELL * GCELL * 2]; // 64b/cell

    // ---- annotation load first (critical path to the first barrier) ----
    float4 an_raw;
    if (tid < NUM_M)
        an_raw = ((const float4*)(ann + (size_t)b * NUM_M * 4))[tid];

    // ---- zero grid masks: 512 words, one per thread ----
    s_mask[tid] = 0u;

    // ---- anchor loads, then cls/reg; sched_barrier pins them above the loop
    float ax[APT], ay[APT], aal[APT];
    #pragma unroll
    for (int j = 0; j < APT; ++j) {
        const int a  = base + tid + j * BLK;
        const int ac = min(a, A - 1);                  // clamp for safety
        const float* ap = anc + 3 * (size_t)ac;
        ax[j] = ap[0]; ay[j] = ap[1]; aal[j] = ap[2];
    }
    float4 cv[APT];
    float rx[APT], ry[APT], ra[APT];
    #pragma unroll
    for (int j = 0; j < APT; ++j) {
        const int a  = base + tid + j * BLK;
        const int ac = min(a, A - 1);
        cv[j] = *(const float4*)(cls + ((size_t)b * A + ac) * NUM_C);
        const float* rp = reg + ((size_t)b * A + ac) * 3;
        rx[j] = rp[0]; ry[j] = rp[1]; ra[j] = rp[2];
    }
    __builtin_amdgcn_sched_barrier(0);                 // loads stay above

    __syncthreads();                                   // masks zeroed

    // ---- build grid: thread m stamps annotation m into dilated cells ----
    if (tid < NUM_M) {
        const float4 an = an_raw;
        s_ann[tid] = an;
        if (an.w != -1.0f) {
            const int cx0 = max(0, (int)((an.x - DILATE_R) * 0.03125f));
            const int cx1 = min(GCELL - 1, (int)((an.x + DILATE_R) * 0.03125f));
            const int cy0 = max(0, (int)((an.y - DILATE_R) * 0.03125f));
            const int cy1 = min(GCELL - 1, (int)((an.y + DILATE_R) * 0.03125f));
            const unsigned int bit  = 1u << (tid & 31);
            const int          word = tid >> 5;
            for (int cy = cy0; cy <= cy1; ++cy) {
                for (int cx = cx0; cx <= cx1; ++cx) {
                    const float ddx = an.x - (cx * 32.0f + 16.0f);
                    const float ddy = an.y - (cy * 32.0f + 16.0f);
                    if (fmaf(ddx, ddx, ddy * ddy) <= DILATE_R2)
                        atomicOr(&s_mask[(cy * GCELL + cx) * 2 + word], bit);
                }
            }
        }
    }
    __syncthreads();

    float cls_s = 0.0f, xy_s = 0.0f, ang_s = 0.0f, pos_s = 0.0f;

    #pragma unroll
    for (int j = 0; j < APT; ++j) {
        const int a = base + tid + j * BLK;

        // ---- candidate scan: own cell's bitmask (avg ~1.6 set bits) ----
        const int cx = min(GCELL - 1, (int)(ax[j] * 0.03125f));
        const int cy = min(GCELL - 1, (int)(ay[j] * 0.03125f));
        const int ci = (cy * GCELL + cx) * 2;
        unsigned int w0 = s_mask[ci];
        unsigned int w1 = s_mask[ci + 1];

        float best = 1e30f;
        int   besti = 0;
        while (w0) {
            const int m = __ffs(w0) - 1;               // ascending m: first-min wins
            w0 &= w0 - 1;
            const float4 an = s_ann[m];
            const float dx = ax[j] - an.x;
            const float dy = ay[j] - an.y;
            const float d2 = fmaf(dx, dx, dy * dy);
            if (d2 < best) { best = d2; besti = m; }
        }
        while (w1) {
            const int m = (__ffs(w1) - 1) + 32;
            w1 &= w1 - 1;
            const float4 an = s_ann[m];
            const float dx = ax[j] - an.x;
            const float dy = ay[j] - an.y;
            const float d2 = fmaf(dx, dx, dy * dy);
            if (d2 < best) { best = d2; besti = m; }
        }

        if (a >= A) continue;

        const float4 ba  = s_ann[besti];   // exact argmin whenever best < 900
        const float  dal = fabsf(aal[j] - ba.z);

        const bool positive   = (best < MAX_POS_D2) && (dal < MAX_ANG);
        const bool background = (best >= BG_POS_D2) || (dal >= BG_ANG);

        int label = (int)ba.w;                         // trunc = astype(int32)
        label = min(max(label, 0), NUM_C - 1);

        // ----- classification (focal) loss -----
        const float cc[4] = {cv[j].x, cv[j].y, cv[j].z, cv[j].w};
        float acc = 0.0f;
        #pragma unroll
        for (int c = 0; c < NUM_C; ++c) {
            const float p = fminf(fmaxf(cc[c], EPS_C), 1.0f - EPS_C);
            const bool is1  = positive && (c == label);    // t == 1
            const float r   = is1 ? (1.0f - p) : p;
            const float af  = is1 ? ALPHA_C : (1.0f - ALPHA_C);
            const float omr = is1 ? p : (1.0f - p);        // 1 - r, >= EPS
            acc += af * r * r * (-__logf(omr));
        }
        cls_s += (positive || background) ? acc : 0.0f;    // t == -1 ignored

        // ----- regression loss (positives only; argmin exact here) -----
        if (positive) {
            pos_s += 1.0f;
            const float dxr = fabsf((ba.x - ax[j]) - rx[j]);
            const float dyr = fabsf((ba.y - ay[j]) - ry[j]);
            const float lx = (dxr <= 1.0f / 9.0f) ? 4.5f * dxr * dxr : dxr - 1.0f / 18.0f;
            const float ly = (dyr <= 1.0f / 9.0f) ? 4.5f * dyr * dyr : dyr - 1.0f / 18.0f;
            xy_s += lx + ly;
            const float dar = fabsf((ba.z - aal[j]) - ra[j]);
            ang_s += fmaxf((dar - 10.0f) * 0.2f, 0.0f);
        }
    }

    // ----- block reduction: wave64 shuffle -> LDS -> per-block slot store -----
    #pragma unroll
    for (int off = 32; off > 0; off >>= 1) {
        cls_s += __shfl_down(cls_s, off, 64);
        xy_s  += __shfl_down(xy_s,  off, 64);
        ang_s += __shfl_down(ang_s, off, 64);
        pos_s += __shfl_down(pos_s, off, 64);
    }
    __shared__ float s_red[BLK / 64][4];
    __shared__ int   s_last;
    const int wave   = tid >> 6;
    const int lane64 = tid & 63;
    if (lane64 == 0) {
        s_red[wave][0] = cls_s;
        s_red[wave][1] = xy_s;
        s_red[wave][2] = ang_s;
        s_red[wave][3] = pos_s;
    }
    __syncthreads();

    if (tid == 0) {
        float c0 = 0.0f, c1 = 0.0f, c2 = 0.0f, c3 = 0.0f;
        #pragma unroll
        for (int w = 0; w < BLK / 64; ++w) {
            c0 += s_red[w][0];
            c1 += s_red[w][1];
            c2 += s_red[w][2];
            c3 += s_red[w][3];
        }
        double* slot = ws + 16 + 4 * (size_t)(b * gridx + blockIdx.x);
        __hip_atomic_store(&slot[0], (double)c0, __ATOMIC_RELAXED, __HIP_MEMORY_SCOPE_AGENT);
        __hip_atomic_store(&slot[1], (double)c1, __ATOMIC_RELAXED, __HIP_MEMORY_SCOPE_AGENT);
        __hip_atomic_store(&slot[2], (double)c2, __ATOMIC_RELAXED, __HIP_MEMORY_SCOPE_AGENT);
        __hip_atomic_store(&slot[3], (double)c3, __ATOMIC_RELAXED, __HIP_MEMORY_SCOPE_AGENT);
        int* counter = (int*)ws;
        const int old = __hip_atomic_fetch_add(counter, 1, __ATOMIC_ACQ_REL,
                                               __HIP_MEMORY_SCOPE_AGENT);
        s_last = (old == total_blocks - 1);
    }
    __syncthreads();

    // ----- fused finalize: last block reduces all slots -----
    if (s_last) {
        __threadfence();
        const int bb   = tid >> 6;                 // 8 batches x 64 lanes
        const int lane = tid & 63;
        double p0 = 0.0, p1 = 0.0, p2 = 0.0, p3 = 0.0;
        for (int s = lane; s < gridx; s += 64) {
            const double* sl = ws + 16 + 4 * (size_t)(bb * gridx + s);
            p0 += __hip_atomic_load(&sl[0], __ATOMIC_RELAXED, __HIP_MEMORY_SCOPE_AGENT);
            p1 += __hip_atomic_load(&sl[1], __ATOMIC_RELAXED, __HIP_MEMORY_SCOPE_AGENT);
            p2 += __hip_atomic_load(&sl[2], __ATOMIC_RELAXED, __HIP_MEMORY_SCOPE_AGENT);
            p3 += __hip_atomic_load(&sl[3], __ATOMIC_RELAXED, __HIP_MEMORY_SCOPE_AGENT);
        }
        #pragma unroll
        for (int off = 32; off > 0; off >>= 1) {
            p0 += __shfl_down(p0, off, 64);
            p1 += __shfl_down(p1, off, 64);
            p2 += __shfl_down(p2, off, 64);
            p3 += __shfl_down(p3, off, 64);
        }
        __shared__ double s_fin[NUM_B][4];
        if (lane == 0) {
            s_fin[bb][0] = p0; s_fin[bb][1] = p1;
            s_fin[bb][2] = p2; s_fin[bb][3] = p3;
        }
        __syncthreads();
        if (tid == 0) {
            double sc = 0.0, sx = 0.0, sg = 0.0;
            #pragma unroll
            for (int k = 0; k < NUM_B; ++k) {
                const double denom = fmax(s_fin[k][3], 1.0);
                sc += s_fin[k][0] / denom;
                sx += s_fin[k][1] / (2.0 * denom);
                sg += s_fin[k][2] / denom;
            }
            out[0] = (float)(sc / (double)NUM_B);
            out[1] = (float)(sx / (double)NUM_B);
            out[2] = (float)(sg / (double)NUM_B);
        }
    }
}

extern "C" void kernel_launch(void* const* d_in, const int* in_sizes, int n_in,
                              void* d_out, int out_size, void* d_ws, size_t ws_size,
                              hipStream_t stream)
{
    const float* cls = (const float*)d_in[0];   // (B, A, 4)
    const float* reg = (const float*)d_in[1];   // (B, A, 3)
    const float* anc = (const float*)d_in[2];   // (1, A, 3)
    const float* ann = (const float*)d_in[3];   // (B, M, 4)
    const int A = in_sizes[2] / 3;

    double* ws = (double*)d_ws;
    // only the counter line needs zeroing; slots are fully overwritten
    hipMemsetAsync(d_ws, 0, 128, stream);

    dim3 grid((A + BLK * APT - 1) / (BLK * APT), NUM_B);   // 32 x 8 = 256 blocks
    focal_main<<<grid, BLK, 0, stream>>>(cls, reg, anc, ann, ws, (float*)d_out,
                                         A, (int)grid.x);
}